// Round 11
// baseline (257.369 us; speedup 1.0000x reference)
//
#include <hip/hip_runtime.h>
#include <hip/hip_cooperative_groups.h>
#include <stdint.h>

#define SS 4096     // tokens per batch (H*W)
#define CC 64       // channels
#define BB 16       // batch

namespace cg = cooperative_groups;

typedef unsigned short u16;
typedef __attribute__((ext_vector_type(8))) __bf16 bf16x8;
typedef __attribute__((ext_vector_type(8))) short short8;
typedef __attribute__((ext_vector_type(4))) float f32x4;

// pack two f32 -> two bf16 in one u32 (low = a, high = b), round-half-up
__device__ __forceinline__ uint32_t pkbf(float a, float b) {
    uint32_t ua = __float_as_uint(a) + 0x8000u;
    uint32_t ub = __float_as_uint(b) + 0x8000u;
    return __builtin_amdgcn_perm(ub, ua, 0x07060302u);
}

// load 8 consecutive fp32 -> bf16x8 fragment (L2-hot)
__device__ __forceinline__ bf16x8 ldw8(const float* p) {
    f32x4 lo = *(const f32x4*)(p);
    f32x4 hi = *(const f32x4*)(p + 4);
    union { uint32_t u[4]; bf16x8 v; } r;
    r.u[0] = pkbf(lo[0], lo[1]);
    r.u[1] = pkbf(lo[2], lo[3]);
    r.u[2] = pkbf(hi[0], hi[1]);
    r.u[3] = pkbf(hi[2], hi[3]);
    return r.v;
}

// ---------------------------------------------------------------------------
// kv_kernel (fallback path): x -> K[B,S,C], VT[B,C,S] bf16. R9 qkv minus Q.
// 64 s/block, grid 1024 (4 blocks/CU).
// ---------------------------------------------------------------------------
__global__ __launch_bounds__(256, 4) void kv_kernel(
    const float* __restrict__ x,
    const float* __restrict__ kw, const float* __restrict__ kb,
    const float* __restrict__ vw, const float* __restrict__ vb,
    u16* __restrict__ K, u16* __restrict__ VT)
{
    const int b    = blockIdx.x & 15;
    const int s0   = (blockIdx.x >> 4) << 6;
    const int tid  = threadIdx.x;
    const int w    = tid >> 6;
    const int lane = tid & 63;
    const int lq   = lane & 15;
    const int quad = lane >> 4;

    __shared__ u16 wt[2][64 * 72];
    __shared__ u16 xt[64 * 72];

    for (int m = 0; m < 2; ++m) {
        const float* wsrc = (m == 0) ? kw : vw;
#pragma unroll
        for (int i = 0; i < 8; ++i) {
            int p  = tid + (i << 8);
            int o  = p >> 5;
            int cp = p & 31;
            const float* wp = wsrc + o * 64 + cp * 2;
            ((uint32_t*)&wt[m][o * 72])[cp] = pkbf(wp[0], wp[1]);
        }
    }
    {
        const int sl = tid & 63;
        const int g  = tid >> 6;
        const float* xp = x + (size_t)b * CC * SS + s0 + sl;
#pragma unroll
        for (int i = 0; i < 8; ++i) {
            int p = g + (i << 2);
            float f0 = xp[(size_t)(2 * p) * SS];
            float f1 = xp[(size_t)(2 * p + 1) * SS];
            ((uint32_t*)&xt[sl * 72])[p] = pkbf(f0, f1);
        }
    }
    __syncthreads();

    bf16x8 a0 = *(const bf16x8*)&xt[(w * 16 + lq) * 72 + quad * 8];
    bf16x8 a1 = *(const bf16x8*)&xt[(w * 16 + lq) * 72 + 32 + quad * 8];
    __syncthreads();

    u16* bb = xt + w * (16 * 72);

    for (int m = 0; m < 2; ++m) {
        const float* bsrc = (m == 0) ? kb : vb;
        bf16x8 bfr[2][4];
#pragma unroll
        for (int kc = 0; kc < 2; ++kc)
#pragma unroll
            for (int nt = 0; nt < 4; ++nt)
                bfr[kc][nt] = *(const bf16x8*)&wt[m][(nt * 16 + lq) * 72 + kc * 32 + quad * 8];

        f32x4 acc[4];
#pragma unroll
        for (int nt = 0; nt < 4; ++nt) {
            float bv = bsrc[nt * 16 + lq];
            acc[nt] = (f32x4){bv, bv, bv, bv};
        }
#pragma unroll
        for (int nt = 0; nt < 4; ++nt) {
            acc[nt] = __builtin_amdgcn_mfma_f32_16x16x32_bf16(a0, bfr[0][nt], acc[nt], 0, 0, 0);
            acc[nt] = __builtin_amdgcn_mfma_f32_16x16x32_bf16(a1, bfr[1][nt], acc[nt], 0, 0, 0);
        }

        if (m == 1) {
#pragma unroll
            for (int nt = 0; nt < 4; ++nt) {
                int c = nt * 16 + lq;
                uint2 pv;
                pv.x = pkbf(acc[nt][0], acc[nt][1]);
                pv.y = pkbf(acc[nt][2], acc[nt][3]);
                *(uint2*)(VT + ((size_t)(b * CC + c)) * SS + s0 + w * 16 + quad * 4) = pv;
            }
        } else {
#pragma unroll
            for (int nt = 0; nt < 4; ++nt)
#pragma unroll
                for (int r = 0; r < 4; ++r)
                    bb[(quad * 4 + r) * 72 + nt * 16 + lq] =
                        (u16)((__float_as_uint(acc[nt][r]) + 0x8000u) >> 16);

            const int row = lane >> 2;
            const int ch  = (lane & 3) << 4;
            short8 v0 = *(const short8*)&bb[row * 72 + ch];
            short8 v1 = *(const short8*)&bb[row * 72 + ch + 8];
            u16* dst = K + ((size_t)(b * SS + s0 + w * 16 + row)) * CC + ch;
            *(short8*)dst = v0;
            *(short8*)(dst + 8) = v1;
        }
    }
}

// ---------------------------------------------------------------------------
// fused_kernel<COOP>: grid 512 x 256 thr.
//  COOP=true : phase A = full QKV for my 128-s slice (K,VT -> global, Q ->
//              LDS only), grid.sync(), phase B = R9 flash + fused out-proj.
//  COOP=false: phase A = Q only (K,VT come from kv_kernel), no grid sync.
// ---------------------------------------------------------------------------
template <bool COOP>
__global__ __launch_bounds__(256, 2) void fused_kernel(
    const float* __restrict__ x,
    const float* __restrict__ qw, const float* __restrict__ qb,
    const float* __restrict__ kw, const float* __restrict__ kb,
    const float* __restrict__ vw, const float* __restrict__ vb,
    const float* __restrict__ ow, const float* __restrict__ ob,
    u16* __restrict__ K, u16* __restrict__ VT, float* __restrict__ out)
{
    const int b    = blockIdx.x & 15;          // batch-major for XCD locality
    const int q0   = (blockIdx.x >> 4) << 7;   // my 128 s == my 128 q
    const int tid  = threadIdx.x;
    const int w    = tid >> 6;
    const int lane = tid & 63;
    const int lq   = lane & 15;
    const int quad = lane >> 4;

    // 48 KB, phase-overlaid:
    //  phase A: WT [0,13824) up to 3x64x72 | XT [13824,23040) 128x72
    //  phase B: lds_k [0,8192) | lds_v [8192,16384) | lds_p [16384,24576)
    __shared__ u16 smem[24576];
    u16* WT = smem;
    u16* XT = smem + 13824;

    // ================= PHASE A =================
    const int NW = COOP ? 3 : 1;
    for (int m = 0; m < NW; ++m) {             // COOP order: v,k,q ; else: q
        const float* wsrc = COOP ? ((m == 0) ? vw : ((m == 1) ? kw : qw)) : qw;
#pragma unroll
        for (int i = 0; i < 8; ++i) {
            int p  = tid + (i << 8);           // pair 0..2047
            int o  = p >> 5;
            int cp = p & 31;
            const float* wp = wsrc + o * 64 + cp * 2;
            ((uint32_t*)&WT[m * 4608 + o * 72])[cp] = pkbf(wp[0], wp[1]);
        }
    }
    {   // x-tile transposed: 128 s, coalesced reads
        const int sl = tid & 127;
        const int g  = tid >> 7;
        const float* xp = x + (size_t)b * CC * SS + q0 + sl;
#pragma unroll
        for (int i = 0; i < 16; ++i) {
            int p = g + (i << 1);              // c-pair 0..31
            float f0 = xp[(size_t)(2 * p) * SS];
            float f1 = xp[(size_t)(2 * p + 1) * SS];
            ((uint32_t*)&XT[sl * 72])[p] = pkbf(f0, f1);
        }
    }
    __syncthreads();

    // A-frags for my 32 s-rows (wave-private rows)
    bf16x8 af[2][2];
#pragma unroll
    for (int mt = 0; mt < 2; ++mt) {
        const int srow = w * 32 + mt * 16;
        af[mt][0] = *(const bf16x8*)&XT[(srow + lq) * 72 + quad * 8];
        af[mt][1] = *(const bf16x8*)&XT[(srow + lq) * 72 + 32 + quad * 8];
    }

    const float QSCALE = 0.125f * 1.44269504088896340736f;

    for (int m = 0; m < NW; ++m) {
        const float* bsrc = COOP ? ((m == 0) ? vb : ((m == 1) ? kb : qb)) : qb;
        const u16* wm = WT + m * 4608;
        bf16x8 bfr[2][4];
#pragma unroll
        for (int kc = 0; kc < 2; ++kc)
#pragma unroll
            for (int nt = 0; nt < 4; ++nt)
                bfr[kc][nt] = *(const bf16x8*)&wm[(nt * 16 + lq) * 72 + kc * 32 + quad * 8];

#pragma unroll
        for (int mt = 0; mt < 2; ++mt) {
            const int srow = w * 32 + mt * 16;
            f32x4 acc[4];
#pragma unroll
            for (int nt = 0; nt < 4; ++nt) {
                float bv = bsrc[nt * 16 + lq];
                acc[nt] = (f32x4){bv, bv, bv, bv};
            }
#pragma unroll
            for (int nt = 0; nt < 4; ++nt) {
                acc[nt] = __builtin_amdgcn_mfma_f32_16x16x32_bf16(af[mt][0], bfr[0][nt], acc[nt], 0, 0, 0);
                acc[nt] = __builtin_amdgcn_mfma_f32_16x16x32_bf16(af[mt][1], bfr[1][nt], acc[nt], 0, 0, 0);
            }

            if (COOP && m == 0) {
                // V^T[b][c][s]
#pragma unroll
                for (int nt = 0; nt < 4; ++nt) {
                    int c = nt * 16 + lq;
                    uint2 pv;
                    pv.x = pkbf(acc[nt][0], acc[nt][1]);
                    pv.y = pkbf(acc[nt][2], acc[nt][3]);
                    *(uint2*)(VT + ((size_t)(b * CC + c)) * SS + q0 + srow + quad * 4) = pv;
                }
            } else if (COOP && m == 1) {
                // K via wave-private XT bounce, coalesced store
                u16* bb = XT + srow * 72;
#pragma unroll
                for (int nt = 0; nt < 4; ++nt)
#pragma unroll
                    for (int r = 0; r < 4; ++r)
                        bb[(quad * 4 + r) * 72 + nt * 16 + lq] =
                            (u16)((__float_as_uint(acc[nt][r]) + 0x8000u) >> 16);

                const int row = lane >> 2;
                const int ch  = (lane & 3) << 4;
                short8 v0 = *(const short8*)&bb[row * 72 + ch];
                short8 v1 = *(const short8*)&bb[row * 72 + ch + 8];
                u16* dst = K + ((size_t)(b * SS + q0 + srow + row)) * CC + ch;
                *(short8*)dst = v0;
                *(short8*)(dst + 8) = v1;
            } else {
                // Q (scaled) -> XT rows (block-local only; wave-private rows)
#pragma unroll
                for (int nt = 0; nt < 4; ++nt)
#pragma unroll
                    for (int r = 0; r < 4; ++r)
                        XT[(srow + quad * 4 + r) * 72 + nt * 16 + lq] =
                            (u16)((__float_as_uint(acc[nt][r] * QSCALE) + 0x8000u) >> 16);
            }
        }
    }
    __syncthreads();                           // all Q rows written

    // flash Q B-frags (cross-wave rows)
    bf16x8 qf[2][2];
#pragma unroll
    for (int g = 0; g < 2; ++g) {
        const int row = g * 64 + w * 16 + lq;
        qf[g][0] = *(const bf16x8*)&XT[row * 72 + quad * 8];
        qf[g][1] = *(const bf16x8*)&XT[row * 72 + 32 + quad * 8];
    }

    if constexpr (COOP) {
        cg::this_grid().sync();                // K/VT visible device-wide
    } else {
        __syncthreads();                       // qf reads done before overlay
    }

    // ================= PHASE B: FLASH (R9-verbatim) =================
    u16* lds_k = smem;
    u16* lds_v = smem + 8192;
    u16* lds_p = smem + 16384;

    f32x4 ot[2][4];
#pragma unroll
    for (int g = 0; g < 2; ++g)
#pragma unroll
        for (int ct = 0; ct < 4; ++ct) ot[g][ct] = (f32x4){0.f, 0.f, 0.f, 0.f};
    float lp[2][4] = {{0.f, 0.f, 0.f, 0.f}, {0.f, 0.f, 0.f, 0.f}};

    const int srow = tid >> 2;
    const int a    = tid & 3;
    const u16* kg = K + ((size_t)(b * SS + srow)) * CC + a * 16;
    const u16* vg = VT + ((size_t)(b * CC + srow)) * SS + a * 16;
    const int sw0 = srow * 64 + (((a << 1)    ) ^ (srow & 7)) * 8;
    const int sw1 = srow * 64 + (((a << 1) | 1) ^ (srow & 7)) * 8;

    {   // prologue: tile 0 -> buf 0
        short8 k0 = *(const short8*)(kg);
        short8 k1 = *(const short8*)(kg + 8);
        short8 v0 = *(const short8*)(vg);
        short8 v1 = *(const short8*)(vg + 8);
        *(short8*)&lds_k[sw0] = k0;
        *(short8*)&lds_k[sw1] = k1;
        *(short8*)&lds_v[sw0] = v0;
        *(short8*)&lds_v[sw1] = v1;
    }

    const int lsw = lq & 7;
    u16* pw0 = lds_p + (w << 1) * 1024;
    u16* pw1 = pw0 + 1024;

    for (int kt = 0; kt < 64; ++kt) {
        __syncthreads();
        const int bo = (kt & 1) << 12;

        const int ktn = (kt + 1) & 63;
        const u16* kgn = kg + (size_t)ktn * (64 * CC);
        const u16* vgn = vg + ktn * 64;
        short8 nk0 = *(const short8*)(kgn);
        short8 nk1 = *(const short8*)(kgn + 8);
        short8 nv0 = *(const short8*)(vgn);
        short8 nv1 = *(const short8*)(vgn + 8);

        bf16x8 kf[2][4];
#pragma unroll
        for (int kc = 0; kc < 2; ++kc)
#pragma unroll
            for (int mt = 0; mt < 4; ++mt)
                kf[kc][mt] = *(const bf16x8*)
                    &lds_k[bo + (mt * 16 + lq) * 64 + (((kc << 2) + quad) ^ lsw) * 8];

        f32x4 sa[2][4];
#pragma unroll
        for (int g = 0; g < 2; ++g)
#pragma unroll
            for (int mt = 0; mt < 4; ++mt) sa[g][mt] = (f32x4){0.f, 0.f, 0.f, 0.f};
#pragma unroll
        for (int g = 0; g < 2; ++g)
#pragma unroll
            for (int kc = 0; kc < 2; ++kc)
#pragma unroll
                for (int mt = 0; mt < 4; ++mt)
                    sa[g][mt] = __builtin_amdgcn_mfma_f32_16x16x32_bf16(
                        kf[kc][mt], qf[g][kc], sa[g][mt], 0, 0, 0);

#pragma unroll
        for (int g = 0; g < 2; ++g) {
            u16* pw = g ? pw1 : pw0;
#pragma unroll
            for (int mt = 0; mt < 4; ++mt) {
                float p0 = __builtin_amdgcn_exp2f(sa[g][mt][0]);
                float p1 = __builtin_amdgcn_exp2f(sa[g][mt][1]);
                float p2 = __builtin_amdgcn_exp2f(sa[g][mt][2]);
                float p3 = __builtin_amdgcn_exp2f(sa[g][mt][3]);
                lp[g][0] += p0; lp[g][1] += p1; lp[g][2] += p2; lp[g][3] += p3;
                uint2 pv;
                pv.x = pkbf(p0, p1);
                pv.y = pkbf(p2, p3);
                *(uint2*)&pw[lq * 64 + (((mt * 2 + (quad >> 1)) ^ lsw) << 3) + (quad & 1) * 4] = pv;
            }
        }

        bf16x8 vf[2][4];
#pragma unroll
        for (int kc = 0; kc < 2; ++kc)
#pragma unroll
            for (int ct = 0; ct < 4; ++ct)
                vf[kc][ct] = *(const bf16x8*)
                    &lds_v[bo + (ct * 16 + lq) * 64 + (((kc << 2) + quad) ^ lsw) * 8];

#pragma unroll
        for (int g = 0; g < 2; ++g) {
            const u16* pw = g ? pw1 : pw0;
#pragma unroll
            for (int kc = 0; kc < 2; ++kc) {
                bf16x8 pf = *(const bf16x8*)
                    &pw[lq * 64 + (((kc * 4 + quad) ^ lsw) << 3)];
#pragma unroll
                for (int ct = 0; ct < 4; ++ct)
                    ot[g][ct] = __builtin_amdgcn_mfma_f32_16x16x32_bf16(
                        vf[kc][ct], pf, ot[g][ct], 0, 0, 0);
            }
        }

        const int bn = 4096 - bo;
        *(short8*)&lds_k[bn + sw0] = nk0;
        *(short8*)&lds_k[bn + sw1] = nk1;
        *(short8*)&lds_v[bn + sw0] = nv0;
        *(short8*)&lds_v[bn + sw1] = nv1;
    }

    // ---- fused out-projection epilogue ----
    bf16x8 wf[2][4];
#pragma unroll
    for (int kc = 0; kc < 2; ++kc)
#pragma unroll
        for (int nt = 0; nt < 4; ++nt)
            wf[kc][nt] = ldw8(ow + (nt * 16 + lq) * 64 + kc * 32 + quad * 8);
    float bias[4];
#pragma unroll
    for (int nt = 0; nt < 4; ++nt) bias[nt] = ob[nt * 16 + lq];

#pragma unroll
    for (int g = 0; g < 2; ++g) {
        float l = (lp[g][0] + lp[g][1]) + (lp[g][2] + lp[g][3]);
        l += __shfl_xor(l, 16);
        l += __shfl_xor(l, 32);
        const float inv = 1.0f / l;

        u16* po = g ? pw1 : pw0;
#pragma unroll
        for (int ct = 0; ct < 4; ++ct) {
            uint2 pv;
            pv.x = pkbf(ot[g][ct][0] * inv, ot[g][ct][1] * inv);
            pv.y = pkbf(ot[g][ct][2] * inv, ot[g][ct][3] * inv);
            *(uint2*)&po[lq * 64 + (((ct * 2 + (quad >> 1)) ^ lsw) << 3) + (quad & 1) * 4] = pv;
        }
        bf16x8 oa0 = *(const bf16x8*)&po[lq * 64 + (((0 * 4 + quad) ^ lsw) << 3)];
        bf16x8 oa1 = *(const bf16x8*)&po[lq * 64 + (((1 * 4 + quad) ^ lsw) << 3)];

        f32x4 acc[4];
#pragma unroll
        for (int nt = 0; nt < 4; ++nt)
            acc[nt] = (f32x4){bias[nt], bias[nt], bias[nt], bias[nt]};
#pragma unroll
        for (int nt = 0; nt < 4; ++nt) {
            acc[nt] = __builtin_amdgcn_mfma_f32_16x16x32_bf16(oa0, wf[0][nt], acc[nt], 0, 0, 0);
            acc[nt] = __builtin_amdgcn_mfma_f32_16x16x32_bf16(oa1, wf[1][nt], acc[nt], 0, 0, 0);
        }
#pragma unroll
        for (int nt = 0; nt < 4; ++nt) {
            float* dst = out + ((size_t)(b * CC + nt * 16 + lq)) * SS
                       + q0 + g * 64 + w * 16 + quad * 4;
            *(f32x4*)dst = acc[nt];
        }
    }
}

// ---------------------------------------------------------------------------
extern "C" void kernel_launch(void* const* d_in, const int* in_sizes, int n_in,
                              void* d_out, int out_size, void* d_ws, size_t ws_size,
                              hipStream_t stream)
{
    const float* x  = (const float*)d_in[0];
    const float* qw = (const float*)d_in[1];
    const float* qb = (const float*)d_in[2];
    const float* kw = (const float*)d_in[3];
    const float* kb = (const float*)d_in[4];
    const float* vw = (const float*)d_in[5];
    const float* vb = (const float*)d_in[6];
    const float* ow = (const float*)d_in[7];
    const float* ob = (const float*)d_in[8];
    float* out = (float*)d_out;

    const size_t T = (size_t)BB * SS * CC;
    u16* K  = (u16*)d_ws;
    u16* VT = K + T;

    void* args[] = {(void*)&x, (void*)&qw, (void*)&qb, (void*)&kw, (void*)&kb,
                    (void*)&vw, (void*)&vb, (void*)&ow, (void*)&ob,
                    (void*)&K, (void*)&VT, (void*)&out};
    hipError_t e = hipLaunchCooperativeKernel((void*)&fused_kernel<true>,
                                              dim3(BB * 32), dim3(256),
                                              args, 0, stream);
    if (e != hipSuccess) {
        (void)hipGetLastError();               // clear error state
        kv_kernel<<<dim3(BB * 64), dim3(256), 0, stream>>>(x, kw, kb, vw, vb, K, VT);
        fused_kernel<false><<<dim3(BB * 32), dim3(256), 0, stream>>>(
            x, qw, qb, kw, kb, vw, vb, ow, ob, K, VT, out);
    }
}